// Round 10
// baseline (379.835 us; speedup 1.0000x reference)
//
#include <hip/hip_runtime.h>
#include <hip/hip_bf16.h>

// Problem constants (B=2, M=2048, HS=1024, K=16 heads, D=64)
#define MM   2048
#define HSZ  1024
#define KH   16
#define DH   64

// ===== DIAGNOSTIC ROUND 2: R9 kernels EXACTLY, self-repeated so every
// dispatch lands in rocprof top-5 with true counters. dur sacrificial. =====
#define SPAN_REP 8
#define GEMM_REP 4
#define SORT_REP 4
#define ATTN_REP 16
#define OGEMM_REP 4

typedef __attribute__((ext_vector_type(8))) short bf16x8;
typedef __attribute__((ext_vector_type(4))) float f32x4;
typedef __attribute__((ext_vector_type(8))) unsigned short u16x8;

#define GLOAD_LDS16(gp, lp) \
    __builtin_amdgcn_global_load_lds( \
        (const __attribute__((address_space(1))) unsigned int*)(gp), \
        (__attribute__((address_space(3))) unsigned int*)(lp), 16, 0, 0)

__device__ __forceinline__ unsigned short f2bf(float x) {
    union { float f; unsigned u; } v; v.f = x;
    unsigned r = v.u + 0x7FFFu + ((v.u >> 16) & 1u);
    return (unsigned short)(r >> 16);
}

// ---------------- fused: span projection (blocks 0..511) + weight converts (512..2559) ----------------
__global__ __launch_bounds__(256) void span_cvt(
    const float* __restrict__ h, const float* __restrict__ Wspan,
    const float* __restrict__ Wval, const float* __restrict__ Wout,
    float* __restrict__ mean_, float* __restrict__ soft_,
    unsigned short* __restrict__ h_bf,
    unsigned short* __restrict__ Wval_bf, unsigned short* __restrict__ Wout_bf)
{
    __shared__ float hrow[8][HSZ];
    int t = threadIdx.x;

    if (blockIdx.x >= 512) {            // weight convert part
        int bid = blockIdx.x - 512;
        const float* in = (bid < 1024) ? Wval : Wout;
        unsigned short* out = (bid < 1024) ? Wval_bf : Wout_bf;
        int i = ((bid & 1023) * 256 + t) * 4;
        for (int rep = 0; rep < SPAN_REP; ++rep) {
            float4 v = *(const float4*)(in + i);
            ushort4 o;
            o.x = f2bf(v.x); o.y = f2bf(v.y); o.z = f2bf(v.z); o.w = f2bf(v.w);
            *(ushort4*)(out + i) = o;
        }
        return;
    }

    int row0 = blockIdx.x * 8;
    for (int rep = 0; rep < SPAN_REP; ++rep) {
        __syncthreads();
        #pragma unroll
        for (int i = 0; i < 8; ++i) {
            int li = t + 256 * i;                // float4 id 0..2047
            int r = li >> 8, c4 = (li & 255) * 4;
            float4 hv = *(const float4*)&h[(long)(row0 + r) * HSZ + c4];
            *(float4*)&hrow[r][c4] = hv;
            ushort4 hb;
            hb.x = f2bf(hv.x); hb.y = f2bf(hv.y); hb.z = f2bf(hv.z); hb.w = f2bf(hv.w);
            *(ushort4*)&h_bf[(long)(row0 + r) * HSZ + c4] = hb;
        }
        __syncthreads();
        int o = t >> 3, part = t & 7;            // 32 outputs x 8 partial-lanes
        const float* w = Wspan + o * HSZ;
        float4 acc[8] = {};
        for (int i = 0; i < 32; ++i) {
            int c = part * 4 + i * 32;
            float4 wv = *(const float4*)&w[c];
            #pragma unroll
            for (int r = 0; r < 8; ++r) {
                float4 a = *(const float4*)&hrow[r][c];
                acc[r].x += a.x * wv.x; acc[r].y += a.y * wv.y;
                acc[r].z += a.z * wv.z; acc[r].w += a.w * wv.w;
            }
        }
        #pragma unroll
        for (int r = 0; r < 8; ++r) {
            float s = acc[r].x + acc[r].y + acc[r].z + acc[r].w;
            s += __shfl_xor(s, 1, 64);
            s += __shfl_xor(s, 2, 64);
            s += __shfl_xor(s, 4, 64);
            if (part == 0) {
                int m = row0 + r;
                int b = m >> 11, mm = m & 2047;
                int bk = b * KH + (o >> 1);
                if ((o & 1) == 0) {
                    mean_[bk * MM + mm] = (1.f / (1.f + __expf(-s))) * (float)MM;
                } else {
                    float sp = (s > 15.f) ? s : log1pf(__expf(s));
                    soft_[bk * MM + mm] = sp;
                }
            }
        }
    }
}

// ---------------- shared GEMM core, 64x64 tile (R9 structure) ----------------
#define SROW(li) ((li) >> 3)
#define SCOL(li) ((((li) & 7) ^ (SROW(li) & 7)) * 8)

template<int STORE_BF16>
__device__ __forceinline__ void gemm_core64(
    unsigned short* __restrict__ AsB, unsigned short* __restrict__ BsB,   // each [2][4096]
    const unsigned short* __restrict__ A, const unsigned short* __restrict__ Bm,
    void* __restrict__ Cv, int N, int Kd,
    int bx, int by, int bz, long aZ, long bZ, long cZ)
{
    const unsigned short* Ab = A  + bz * aZ;
    const unsigned short* Bb = Bm + bz * bZ;
    long czoff = bz * cZ;
    int row0 = by * 64;
    int col0 = bx * 64;
    int t = threadIdx.x;
    int wid = t >> 6, l = t & 63;
    int wr = wid >> 1, wc = wid & 1;
    int lr = l & 15, lhi = l >> 4;

    #define STAGE64(buf, k0s) do { \
        unsigned short* As_ = AsB + (buf) * 4096; \
        unsigned short* Bs_ = BsB + (buf) * 4096; \
        int a0 = t, a1 = t + 256; \
        GLOAD_LDS16(Ab + (long)(row0 + SROW(a0)) * Kd + (k0s) + SCOL(a0), As_ + a0 * 8); \
        GLOAD_LDS16(Ab + (long)(row0 + SROW(a1)) * Kd + (k0s) + SCOL(a1), As_ + a1 * 8); \
        GLOAD_LDS16(Bb + (long)(col0 + SROW(a0)) * Kd + (k0s) + SCOL(a0), Bs_ + a0 * 8); \
        GLOAD_LDS16(Bb + (long)(col0 + SROW(a1)) * Kd + (k0s) + SCOL(a1), Bs_ + a1 * 8); \
    } while (0)

    f32x4 acc[2][2] = {};
    int nk = Kd >> 6;

    STAGE64(0, 0);

    for (int ks = 0; ks < nk; ++ks) {
        int cur = ks & 1;
        if (ks + 1 < nk) {
            STAGE64(cur ^ 1, (ks + 1) << 6);
            asm volatile("s_waitcnt vmcnt(4)" ::: "memory");
        } else {
            asm volatile("s_waitcnt vmcnt(0)" ::: "memory");
        }
        __builtin_amdgcn_s_barrier();

        bf16x8 af[2][2], bfr[2][2];
        #pragma unroll
        for (int kk = 0; kk < 2; ++kk) {
            int slotx = ((kk * 4 + lhi) ^ (lr & 7)) << 3;
            #pragma unroll
            for (int i = 0; i < 2; ++i)
                af[kk][i] = *(const bf16x8*)(AsB + cur * 4096 + (wr * 32 + i * 16 + lr) * 64 + slotx);
            #pragma unroll
            for (int j = 0; j < 2; ++j)
                bfr[kk][j] = *(const bf16x8*)(BsB + cur * 4096 + (wc * 32 + j * 16 + lr) * 64 + slotx);
        }
        asm volatile("s_waitcnt lgkmcnt(0)" ::: "memory");
        __builtin_amdgcn_sched_barrier(0);
        __builtin_amdgcn_s_barrier();

        #pragma unroll
        for (int kk = 0; kk < 2; ++kk)
            #pragma unroll
            for (int i = 0; i < 2; ++i)
                #pragma unroll
                for (int j = 0; j < 2; ++j)
                    acc[i][j] = __builtin_amdgcn_mfma_f32_16x16x32_bf16(af[kk][i], bfr[kk][j], acc[i][j], 0, 0, 0);
    }
    #undef STAGE64

    // C/D layout: col = l&15, row = (l>>4)*4 + r_
    #pragma unroll
    for (int i = 0; i < 2; ++i) {
        int rbase = row0 + wr * 32 + i * 16 + lhi * 4;
        #pragma unroll
        for (int j = 0; j < 2; ++j) {
            int cidx = col0 + wc * 32 + j * 16 + lr;
            #pragma unroll
            for (int r_ = 0; r_ < 4; ++r_) {
                long idx = czoff + (long)(rbase + r_) * N + cidx;
                if (STORE_BF16) ((unsigned short*)Cv)[idx] = f2bf(acc[i][j][r_]);
                else            ((float*)Cv)[idx] = acc[i][j][r_];
            }
        }
    }
}

// ---------------- deterministic counting sort of rows by mean/64 (one bk per call) ----------------
__device__ void sort_core(char* smem, const float* __restrict__ mean_,
                          int* __restrict__ perm, int bk)
{
    unsigned short (*hist)[257] = (unsigned short(*)[257])smem;     // 16448 B
    int* binTot = (int*)(smem + 16448);
    int* binStart = binTot + 32;
    int t = threadIdx.x;
    int bins[8];
    #pragma unroll
    for (int i = 0; i < 8; ++i) {
        float mq = mean_[bk * MM + t * 8 + i];
        int b = (int)(mq * (1.f / 64.f));
        bins[i] = min(31, max(0, b));
    }
    for (int b = 0; b < 32; ++b) hist[b][t] = 0;
    __syncthreads();
    #pragma unroll
    for (int i = 0; i < 8; ++i) hist[bins[i]][t]++;   // own column, race-free
    __syncthreads();
    int w = t >> 6, l = t & 63;
    for (int b = w * 8; b < w * 8 + 8; ++b) {
        int carry = 0;
        for (int g = 0; g < 4; ++g) {
            int v = (int)hist[b][g * 64 + l];
            int x = v;
            #pragma unroll
            for (int off = 1; off < 64; off <<= 1) {
                int y = __shfl_up(x, off, 64);
                if (l >= off) x += y;
            }
            hist[b][g * 64 + l] = (unsigned short)(x - v + carry);
            carry += __shfl(x, 63, 64);
        }
        if (l == 0) binTot[b] = carry;
    }
    __syncthreads();
    if (t == 0) {
        int s = 0;
        for (int b = 0; b < 32; ++b) { binStart[b] = s; s += binTot[b]; }
    }
    __syncthreads();
    #pragma unroll
    for (int i = 0; i < 8; ++i) {
        int b = bins[i];
        int prior = 0;
        #pragma unroll
        for (int j = 0; j < 8; ++j) if (j < i && bins[j] == b) prior++;
        int pos = binStart[b] + (int)hist[b][t] + prior;
        perm[bk * MM + pos] = t * 8 + i;
    }
}

// ---------------- value GEMM (blocks 0..1023) + sort (blocks 1024..1055) ----------------
__global__ __launch_bounds__(256) void vgemm_sort(
    const unsigned short* __restrict__ Wval_bf, const unsigned short* __restrict__ h_bf,
    unsigned short* __restrict__ hvT,
    const float* __restrict__ mean_, int* __restrict__ perm)
{
    __shared__ __align__(16) char smem[32768];
    int f = blockIdx.x;
    if (f < 1024) {
        int swz = (f & 7) * 128 + (f >> 3);
        int by = swz & 15, r = swz >> 4;
        int bx = r & 31, bz = r >> 5;
        for (int rep = 0; rep < GEMM_REP; ++rep) {
            __syncthreads();
            gemm_core64<1>((unsigned short*)smem, (unsigned short*)(smem + 16384),
                           Wval_bf, h_bf, hvT, MM, HSZ, bx, by, bz,
                           0L, (long)MM * HSZ, (long)HSZ * MM);
        }
    } else {
        for (int rep = 0; rep < SORT_REP; ++rep) {
            __syncthreads();
            sort_core(smem, mean_, perm, f - 1024);
        }
    }
}

// ---------------- output GEMM standalone ----------------
__global__ __launch_bounds__(256) void ogemm(
    const unsigned short* __restrict__ att, const unsigned short* __restrict__ Wout_bf,
    float* __restrict__ out)
{
    __shared__ __align__(16) unsigned short As[2][4096];
    __shared__ __align__(16) unsigned short Bs[2][4096];
    int f = blockIdx.x;
    int swz = (f & 7) * 128 + (f >> 3);
    int bx = swz & 15, by = (swz >> 4) & 63;
    for (int rep = 0; rep < OGEMM_REP; ++rep) {
        __syncthreads();
        gemm_core64<0>(&As[0][0], &Bs[0][0], att, Wout_bf, out, HSZ, HSZ,
                       bx, by, 0, 0L, 0L, 0L);
    }
}

// ---------------- fused Gaussian attention over mean-sorted rows (dynamic k-range) ----------------
__global__ __launch_bounds__(512) void attn_gauss(
    const float* __restrict__ mean_, const float* __restrict__ soft_,
    const int* __restrict__ perm,
    const unsigned short* __restrict__ hvT, unsigned short* __restrict__ att)
{
    __shared__ __align__(16) unsigned short Vs[2][64 * 64];
    __shared__ float red[2][8];
    int flat = blockIdx.x;                   // 0..511
    int swz = (flat & 7) * 64 + (flat >> 3); // XCD-chunked bijection
    int bk = swz >> 4;                       // 0..31
    int qb = swz & 15;                       // 0..15
    int t = threadIdx.x, wid = t >> 6, l = t & 63;
    int b = bk >> 4, head = bk & 15;
    int lr = l & 15, lhi = l >> 4;
    int slot = qb * 128 + wid * 16 + lr;
    int q = perm[bk * MM + slot];
    float mq  = mean_[bk * MM + q];
    float sq  = soft_[bk * MM + q];
    const unsigned short* Vbase = hvT + (long)bk * DH * MM;

    for (int rep = 0; rep < ATTN_REP; ++rep) {
        __syncthreads();
        // block-level k-tile range from union of per-row windows
        float w = __fsqrt_rn(50.f / sq);
        float lo = mq - w, hi = mq + w;
        #pragma unroll
        for (int off = 1; off < 64; off <<= 1) {
            lo = fminf(lo, __shfl_xor(lo, off, 64));
            hi = fmaxf(hi, __shfl_xor(hi, off, 64));
        }
        if (l == 0) { red[0][wid] = lo; red[1][wid] = hi; }
        __syncthreads();
        float blo = red[0][0], bhi = red[1][0];
        #pragma unroll
        for (int i = 1; i < 8; ++i) {
            blo = fminf(blo, red[0][i]);
            bhi = fmaxf(bhi, red[1][i]);
        }
        blo = fmaxf(blo, 0.f);
        bhi = fmaxf(fminf(bhi, 2047.f), 0.f);
        int kt0 = ((int)blo) >> 6;
        int kt1 = ((int)bhi) >> 6;
        if (kt1 < kt0) kt1 = kt0;

        int sr = t >> 3;
        int sc = (((t & 7) ^ (sr & 7)) * 8);

        f32x4 acc[4] = {};
        float lsum = 0.f;
        int jlane0 = lhi * 8;

        GLOAD_LDS16(Vbase + (long)sr * MM + (kt0 << 6) + sc, &Vs[0][t * 8]);
        __syncthreads();

        for (int kt = kt0; kt <= kt1; ++kt) {
            int cur = (kt - kt0) & 1;
            int k0 = kt << 6;
            if (kt < kt1)
                GLOAD_LDS16(Vbase + (long)sr * MM + (k0 + 64) + sc, &Vs[cur ^ 1][t * 8]);

            float dmin = fmaxf(fmaxf((float)k0 - mq, mq - (float)(k0 + 63)), 0.f);
            bool active = (sq * dmin * dmin) < 50.f;
            if (__ballot(active)) {
                #pragma unroll
                for (int kk = 0; kk < 64; kk += 32) {
                    bf16x8 pfrag;
                    float dbase = (float)(k0 + kk + jlane0) - mq;
                    #pragma unroll
                    for (int jj = 0; jj < 8; ++jj) {
                        float d_ = dbase + (float)jj;
                        float p = __expf(-sq * d_ * d_);
                        lsum += p;
                        pfrag[jj] = (short)f2bf(p);
                    }
                    int slotx = (((kk >> 3) + lhi) ^ (lr & 7)) << 3;
                    #pragma unroll
                    for (int df = 0; df < 4; ++df) {
                        bf16x8 vf = *(const bf16x8*)&Vs[cur][(df * 16 + lr) * 64 + slotx];
                        acc[df] = __builtin_amdgcn_mfma_f32_16x16x32_bf16(pfrag, vf, acc[df], 0, 0, 0);
                    }
                }
            }
            __syncthreads();
        }

        lsum += __shfl_xor(lsum, 16, 64);
        lsum += __shfl_xor(lsum, 32, 64);

        int slot_base = qb * 128 + wid * 16;
        #pragma unroll
        for (int r_ = 0; r_ < 4; ++r_) {
            int qr = lhi * 4 + r_;
            float inv = 1.f / __shfl(lsum, qr, 64);
            int qo = perm[bk * MM + slot_base + qr];
            long orow = ((long)b * MM + qo) * HSZ + head * DH;
            #pragma unroll
            for (int df = 0; df < 4; ++df)
                att[orow + df * 16 + lr] = f2bf(acc[df][r_] * inv);
        }
    }
}

extern "C" void kernel_launch(void* const* d_in, const int* in_sizes, int n_in,
                              void* d_out, int out_size, void* d_ws, size_t ws_size,
                              hipStream_t stream) {
    (void)in_sizes; (void)n_in; (void)out_size; (void)ws_size;
    const float* h     = (const float*)d_in[0];   // (2, 2048, 1024)
    const float* Wspan = (const float*)d_in[1];   // (32, 1024)
    const float* Wval  = (const float*)d_in[2];   // (1024, 1024)
    const float* Wout  = (const float*)d_in[3];   // (1024, 1024)
    float* out = (float*)d_out;                   // (2, 2048, 1024) f32

    char* ws = (char*)d_ws;
    unsigned short* h_bf    = (unsigned short*)(ws);               // 8 MB
    unsigned short* Wval_bf = (unsigned short*)(ws +  8388608);    // 2 MB
    unsigned short* Wout_bf = (unsigned short*)(ws + 10485760);    // 2 MB
    unsigned short* hvT     = (unsigned short*)(ws + 12582912);    // 8 MB
    unsigned short* att     = (unsigned short*)(ws + 20971520);    // 8 MB
    float*          mean_   = (float*)(ws + 29360128);             // 256 KB
    float*          soft_   = (float*)(ws + 29622272);             // 256 KB
    int*            perm    = (int*)(ws + 29884416);               // 256 KB

    span_cvt<<<2560, 256, 0, stream>>>(h, Wspan, Wval, Wout,
                                       mean_, soft_, h_bf, Wval_bf, Wout_bf);

    vgemm_sort<<<1056, 256, 0, stream>>>(Wval_bf, h_bf, hvT, mean_, perm);

    attn_gauss<<<512, 512, 0, stream>>>(mean_, soft_, perm, hvT, att);

    ogemm<<<1024, 256, 0, stream>>>(att, Wout_bf, out);
}

// Round 11
// 66.387 us; speedup vs baseline: 5.7215x; 5.7215x over previous
//
#include <hip/hip_runtime.h>
#include <hip/hip_bf16.h>

// Problem constants (B=2, M=2048, HS=1024, K=16 heads, D=64)
#define MM   2048
#define HSZ  1024
#define KH   16
#define DH   64

typedef __attribute__((ext_vector_type(8))) short bf16x8;
typedef __attribute__((ext_vector_type(4))) float f32x4;
typedef __attribute__((ext_vector_type(8))) unsigned short u16x8;

#define GLOAD_LDS16(gp, lp) \
    __builtin_amdgcn_global_load_lds( \
        (const __attribute__((address_space(1))) unsigned int*)(gp), \
        (__attribute__((address_space(3))) unsigned int*)(lp), 16, 0, 0)

__device__ __forceinline__ unsigned short f2bf(float x) {
    union { float f; unsigned u; } v; v.f = x;
    unsigned r = v.u + 0x7FFFu + ((v.u >> 16) & 1u);
    return (unsigned short)(r >> 16);
}

// ---------------- fused: span projection (blocks 0..1023, 4 rows each) ----------------
// ---------------- + weight converts (blocks 1024..3071)              ----------------
__global__ __launch_bounds__(256) void span_cvt(
    const float* __restrict__ h, const float* __restrict__ Wspan,
    const float* __restrict__ Wval, const float* __restrict__ Wout,
    float* __restrict__ mean_, float* __restrict__ soft_,
    unsigned short* __restrict__ h_bf,
    unsigned short* __restrict__ Wval_bf, unsigned short* __restrict__ Wout_bf)
{
    __shared__ float hrow[4][HSZ];           // 16 KB -> high blocks/CU
    int t = threadIdx.x;

    if (blockIdx.x >= 1024) {                // weight convert part
        int bid = blockIdx.x - 1024;
        const float* in = (bid < 1024) ? Wval : Wout;
        unsigned short* out = (bid < 1024) ? Wval_bf : Wout_bf;
        int i = ((bid & 1023) * 256 + t) * 4;
        float4 v = *(const float4*)(in + i);
        ushort4 o;
        o.x = f2bf(v.x); o.y = f2bf(v.y); o.z = f2bf(v.z); o.w = f2bf(v.w);
        *(ushort4*)(out + i) = o;
        return;
    }

    // span part: 4 rows per block + fused h f32->bf16 convert
    int row0 = blockIdx.x * 4;
    #pragma unroll
    for (int i = 0; i < 4; ++i) {
        int li = t + 256 * i;                // float4 id 0..1023
        int r = li >> 8, c4 = (li & 255) * 4;
        float4 hv = *(const float4*)&h[(long)(row0 + r) * HSZ + c4];
        *(float4*)&hrow[r][c4] = hv;
        ushort4 hb;
        hb.x = f2bf(hv.x); hb.y = f2bf(hv.y); hb.z = f2bf(hv.z); hb.w = f2bf(hv.w);
        *(ushort4*)&h_bf[(long)(row0 + r) * HSZ + c4] = hb;
    }
    __syncthreads();
    int o = t >> 3, part = t & 7;            // 32 outputs x 8 partial-lanes
    const float* w = Wspan + o * HSZ;
    float4 acc[4] = {};
    #pragma unroll 4
    for (int i = 0; i < 32; ++i) {
        int c = part * 4 + i * 32;
        float4 wv = *(const float4*)&w[c];
        #pragma unroll
        for (int r = 0; r < 4; ++r) {
            float4 a = *(const float4*)&hrow[r][c];
            acc[r].x += a.x * wv.x; acc[r].y += a.y * wv.y;
            acc[r].z += a.z * wv.z; acc[r].w += a.w * wv.w;
        }
    }
    #pragma unroll
    for (int r = 0; r < 4; ++r) {
        float s = acc[r].x + acc[r].y + acc[r].z + acc[r].w;
        s += __shfl_xor(s, 1, 64);
        s += __shfl_xor(s, 2, 64);
        s += __shfl_xor(s, 4, 64);
        if (part == 0) {
            int m = row0 + r;
            int b = m >> 11, mm = m & 2047;
            int bk = b * KH + (o >> 1);
            if ((o & 1) == 0) {
                mean_[bk * MM + mm] = (1.f / (1.f + __expf(-s))) * (float)MM;
            } else {
                float sp = (s > 15.f) ? s : log1pf(__expf(s));
                soft_[bk * MM + mm] = sp;
            }
        }
    }
}

// ---------------- shared GEMM core, 64x64 tile (R9 structure, unchanged) ----------------
#define SROW(li) ((li) >> 3)
#define SCOL(li) ((((li) & 7) ^ (SROW(li) & 7)) * 8)

template<int STORE_BF16>
__device__ __forceinline__ void gemm_core64(
    unsigned short* __restrict__ AsB, unsigned short* __restrict__ BsB,   // each [2][4096]
    const unsigned short* __restrict__ A, const unsigned short* __restrict__ Bm,
    void* __restrict__ Cv, int N, int Kd,
    int bx, int by, int bz, long aZ, long bZ, long cZ)
{
    const unsigned short* Ab = A  + bz * aZ;
    const unsigned short* Bb = Bm + bz * bZ;
    long czoff = bz * cZ;
    int row0 = by * 64;
    int col0 = bx * 64;
    int t = threadIdx.x;
    int wid = t >> 6, l = t & 63;
    int wr = wid >> 1, wc = wid & 1;
    int lr = l & 15, lhi = l >> 4;

    #define STAGE64(buf, k0s) do { \
        unsigned short* As_ = AsB + (buf) * 4096; \
        unsigned short* Bs_ = BsB + (buf) * 4096; \
        int a0 = t, a1 = t + 256; \
        GLOAD_LDS16(Ab + (long)(row0 + SROW(a0)) * Kd + (k0s) + SCOL(a0), As_ + a0 * 8); \
        GLOAD_LDS16(Ab + (long)(row0 + SROW(a1)) * Kd + (k0s) + SCOL(a1), As_ + a1 * 8); \
        GLOAD_LDS16(Bb + (long)(col0 + SROW(a0)) * Kd + (k0s) + SCOL(a0), Bs_ + a0 * 8); \
        GLOAD_LDS16(Bb + (long)(col0 + SROW(a1)) * Kd + (k0s) + SCOL(a1), Bs_ + a1 * 8); \
    } while (0)

    f32x4 acc[2][2] = {};
    int nk = Kd >> 6;

    STAGE64(0, 0);

    for (int ks = 0; ks < nk; ++ks) {
        int cur = ks & 1;
        if (ks + 1 < nk) {
            STAGE64(cur ^ 1, (ks + 1) << 6);
            asm volatile("s_waitcnt vmcnt(4)" ::: "memory");
        } else {
            asm volatile("s_waitcnt vmcnt(0)" ::: "memory");
        }
        __builtin_amdgcn_s_barrier();

        bf16x8 af[2][2], bfr[2][2];
        #pragma unroll
        for (int kk = 0; kk < 2; ++kk) {
            int slotx = ((kk * 4 + lhi) ^ (lr & 7)) << 3;
            #pragma unroll
            for (int i = 0; i < 2; ++i)
                af[kk][i] = *(const bf16x8*)(AsB + cur * 4096 + (wr * 32 + i * 16 + lr) * 64 + slotx);
            #pragma unroll
            for (int j = 0; j < 2; ++j)
                bfr[kk][j] = *(const bf16x8*)(BsB + cur * 4096 + (wc * 32 + j * 16 + lr) * 64 + slotx);
        }
        asm volatile("s_waitcnt lgkmcnt(0)" ::: "memory");
        __builtin_amdgcn_sched_barrier(0);
        __builtin_amdgcn_s_barrier();

        #pragma unroll
        for (int kk = 0; kk < 2; ++kk)
            #pragma unroll
            for (int i = 0; i < 2; ++i)
                #pragma unroll
                for (int j = 0; j < 2; ++j)
                    acc[i][j] = __builtin_amdgcn_mfma_f32_16x16x32_bf16(af[kk][i], bfr[kk][j], acc[i][j], 0, 0, 0);
    }
    #undef STAGE64

    // C/D layout: col = l&15, row = (l>>4)*4 + r_
    #pragma unroll
    for (int i = 0; i < 2; ++i) {
        int rbase = row0 + wr * 32 + i * 16 + lhi * 4;
        #pragma unroll
        for (int j = 0; j < 2; ++j) {
            int cidx = col0 + wc * 32 + j * 16 + lr;
            #pragma unroll
            for (int r_ = 0; r_ < 4; ++r_) {
                long idx = czoff + (long)(rbase + r_) * N + cidx;
                if (STORE_BF16) ((unsigned short*)Cv)[idx] = f2bf(acc[i][j][r_]);
                else            ((float*)Cv)[idx] = acc[i][j][r_];
            }
        }
    }
}

// ---------------- deterministic counting sort of rows by mean/64 (one bk per call) ----------------
__device__ void sort_core(char* smem, const float* __restrict__ mean_,
                          int* __restrict__ perm, int bk)
{
    unsigned short (*hist)[257] = (unsigned short(*)[257])smem;     // 16448 B
    int* binTot = (int*)(smem + 16448);
    int* binStart = binTot + 32;
    int t = threadIdx.x;
    int bins[8];
    #pragma unroll
    for (int i = 0; i < 8; ++i) {
        float mq = mean_[bk * MM + t * 8 + i];
        int b = (int)(mq * (1.f / 64.f));
        bins[i] = min(31, max(0, b));
    }
    for (int b = 0; b < 32; ++b) hist[b][t] = 0;
    __syncthreads();
    #pragma unroll
    for (int i = 0; i < 8; ++i) hist[bins[i]][t]++;   // own column, race-free
    __syncthreads();
    int w = t >> 6, l = t & 63;
    for (int b = w * 8; b < w * 8 + 8; ++b) {
        int carry = 0;
        for (int g = 0; g < 4; ++g) {
            int v = (int)hist[b][g * 64 + l];
            int x = v;
            #pragma unroll
            for (int off = 1; off < 64; off <<= 1) {
                int y = __shfl_up(x, off, 64);
                if (l >= off) x += y;
            }
            hist[b][g * 64 + l] = (unsigned short)(x - v + carry);
            carry += __shfl(x, 63, 64);
        }
        if (l == 0) binTot[b] = carry;
    }
    __syncthreads();
    if (t == 0) {
        int s = 0;
        for (int b = 0; b < 32; ++b) { binStart[b] = s; s += binTot[b]; }
    }
    __syncthreads();
    #pragma unroll
    for (int i = 0; i < 8; ++i) {
        int b = bins[i];
        int prior = 0;
        #pragma unroll
        for (int j = 0; j < 8; ++j) if (j < i && bins[j] == b) prior++;
        int pos = binStart[b] + (int)hist[b][t] + prior;
        perm[bk * MM + pos] = t * 8 + i;
    }
}

// ---------------- value GEMM (blocks 0..1023) + sort (blocks 1024..1055) ----------------
__global__ __launch_bounds__(256) void vgemm_sort(
    const unsigned short* __restrict__ Wval_bf, const unsigned short* __restrict__ h_bf,
    unsigned short* __restrict__ hvT,
    const float* __restrict__ mean_, int* __restrict__ perm)
{
    __shared__ __align__(16) char smem[32768];
    int f = blockIdx.x;
    if (f < 1024) {
        int swz = (f & 7) * 128 + (f >> 3);
        int by = swz & 15, r = swz >> 4;
        int bx = r & 31, bz = r >> 5;
        gemm_core64<1>((unsigned short*)smem, (unsigned short*)(smem + 16384),
                       Wval_bf, h_bf, hvT, MM, HSZ, bx, by, bz,
                       0L, (long)MM * HSZ, (long)HSZ * MM);
    } else {
        sort_core(smem, mean_, perm, f - 1024);
    }
}

// ---------------- output GEMM standalone ----------------
__global__ __launch_bounds__(256) void ogemm(
    const unsigned short* __restrict__ att, const unsigned short* __restrict__ Wout_bf,
    float* __restrict__ out)
{
    __shared__ __align__(16) unsigned short As[2][4096];
    __shared__ __align__(16) unsigned short Bs[2][4096];
    int f = blockIdx.x;
    int swz = (f & 7) * 128 + (f >> 3);
    int bx = swz & 15, by = (swz >> 4) & 63;
    gemm_core64<0>(&As[0][0], &Bs[0][0], att, Wout_bf, out, HSZ, HSZ,
                   bx, by, 0, 0L, 0L, 0L);
}

// ---------------- fused Gaussian attention over mean-sorted rows (dynamic k-range) ----------------
__global__ __launch_bounds__(512) void attn_gauss(
    const float* __restrict__ mean_, const float* __restrict__ soft_,
    const int* __restrict__ perm,
    const unsigned short* __restrict__ hvT, unsigned short* __restrict__ att)
{
    __shared__ __align__(16) unsigned short Vs[2][64 * 64];
    __shared__ float red[2][8];
    int flat = blockIdx.x;                   // 0..511
    int swz = (flat & 7) * 64 + (flat >> 3); // XCD-chunked bijection
    int bk = swz >> 4;                       // 0..31
    int qb = swz & 15;                       // 0..15
    int t = threadIdx.x, wid = t >> 6, l = t & 63;
    int b = bk >> 4, head = bk & 15;
    int lr = l & 15, lhi = l >> 4;
    int slot = qb * 128 + wid * 16 + lr;
    int q = perm[bk * MM + slot];
    float mq  = mean_[bk * MM + q];
    float sq  = soft_[bk * MM + q];
    const unsigned short* Vbase = hvT + (long)bk * DH * MM;

    // block-level k-tile range from union of per-row windows (same exp(-50) cutoff)
    float w = __fsqrt_rn(50.f / sq);         // sq==0 -> inf -> full range
    float lo = mq - w, hi = mq + w;
    #pragma unroll
    for (int off = 1; off < 64; off <<= 1) {
        lo = fminf(lo, __shfl_xor(lo, off, 64));
        hi = fmaxf(hi, __shfl_xor(hi, off, 64));
    }
    if (l == 0) { red[0][wid] = lo; red[1][wid] = hi; }
    __syncthreads();
    float blo = red[0][0], bhi = red[1][0];
    #pragma unroll
    for (int i = 1; i < 8; ++i) {
        blo = fminf(blo, red[0][i]);
        bhi = fmaxf(bhi, red[1][i]);
    }
    blo = fmaxf(blo, 0.f);
    bhi = fmaxf(fminf(bhi, 2047.f), 0.f);
    int kt0 = ((int)blo) >> 6;
    int kt1 = ((int)bhi) >> 6;
    if (kt1 < kt0) kt1 = kt0;

    int sr = t >> 3;
    int sc = (((t & 7) ^ (sr & 7)) * 8);

    f32x4 acc[4] = {};
    float lsum = 0.f;
    int jlane0 = lhi * 8;

    GLOAD_LDS16(Vbase + (long)sr * MM + (kt0 << 6) + sc, &Vs[0][t * 8]);
    __syncthreads();

    for (int kt = kt0; kt <= kt1; ++kt) {
        int cur = (kt - kt0) & 1;
        int k0 = kt << 6;
        if (kt < kt1)
            GLOAD_LDS16(Vbase + (long)sr * MM + (k0 + 64) + sc, &Vs[cur ^ 1][t * 8]);

        // per-wave skip (range may be driven by an outlier row in another wave)
        float dmin = fmaxf(fmaxf((float)k0 - mq, mq - (float)(k0 + 63)), 0.f);
        bool active = (sq * dmin * dmin) < 50.f;   // exp(-50) ~ 2e-22
        if (__ballot(active)) {
            #pragma unroll
            for (int kk = 0; kk < 64; kk += 32) {
                bf16x8 pfrag;
                float dbase = (float)(k0 + kk + jlane0) - mq;
                #pragma unroll
                for (int jj = 0; jj < 8; ++jj) {
                    float d_ = dbase + (float)jj;
                    float p = __expf(-sq * d_ * d_);
                    lsum += p;
                    pfrag[jj] = (short)f2bf(p);
                }
                int slotx = (((kk >> 3) + lhi) ^ (lr & 7)) << 3;
                #pragma unroll
                for (int df = 0; df < 4; ++df) {
                    bf16x8 vf = *(const bf16x8*)&Vs[cur][(df * 16 + lr) * 64 + slotx];
                    acc[df] = __builtin_amdgcn_mfma_f32_16x16x32_bf16(pfrag, vf, acc[df], 0, 0, 0);
                }
            }
        }
        __syncthreads();
    }

    lsum += __shfl_xor(lsum, 16, 64);
    lsum += __shfl_xor(lsum, 32, 64);

    int slot_base = qb * 128 + wid * 16;
    #pragma unroll
    for (int r_ = 0; r_ < 4; ++r_) {
        int qr = lhi * 4 + r_;
        float inv = 1.f / __shfl(lsum, qr, 64);
        int qo = perm[bk * MM + slot_base + qr];
        long orow = ((long)b * MM + qo) * HSZ + head * DH;
        #pragma unroll
        for (int df = 0; df < 4; ++df)
            att[orow + df * 16 + lr] = f2bf(acc[df][r_] * inv);
    }
}

extern "C" void kernel_launch(void* const* d_in, const int* in_sizes, int n_in,
                              void* d_out, int out_size, void* d_ws, size_t ws_size,
                              hipStream_t stream) {
    (void)in_sizes; (void)n_in; (void)out_size; (void)ws_size;
    const float* h     = (const float*)d_in[0];   // (2, 2048, 1024)
    const float* Wspan = (const float*)d_in[1];   // (32, 1024)
    const float* Wval  = (const float*)d_in[2];   // (1024, 1024)
    const float* Wout  = (const float*)d_in[3];   // (1024, 1024)
    float* out = (float*)d_out;                   // (2, 2048, 1024) f32

    char* ws = (char*)d_ws;
    unsigned short* h_bf    = (unsigned short*)(ws);               // 8 MB
    unsigned short* Wval_bf = (unsigned short*)(ws +  8388608);    // 2 MB
    unsigned short* Wout_bf = (unsigned short*)(ws + 10485760);    // 2 MB
    unsigned short* hvT     = (unsigned short*)(ws + 12582912);    // 8 MB
    unsigned short* att     = (unsigned short*)(ws + 20971520);    // 8 MB
    float*          mean_   = (float*)(ws + 29360128);             // 256 KB
    float*          soft_   = (float*)(ws + 29622272);             // 256 KB
    int*            perm    = (int*)(ws + 29884416);               // 256 KB

    // 1. span params (1024 blocks x 4 rows) + h convert + weight converts
    span_cvt<<<3072, 256, 0, stream>>>(h, Wspan, Wval, Wout,
                                       mean_, soft_, h_bf, Wval_bf, Wout_bf);

    // 2. value GEMM (1024 blocks, 64x64 tiles) + row sort (32 blocks)
    vgemm_sort<<<1056, 256, 0, stream>>>(Wval_bf, h_bf, hvT, mean_, perm);

    // 3. fused Gaussian attention -> att (B, M, HS) bf16
    attn_gauss<<<512, 512, 0, stream>>>(mean_, soft_, perm, hvT, att);

    // 4. output GEMM: out[b*2048+m][n] = sum_c att[b,m,c] * Wout[n,c]
    ogemm<<<1024, 256, 0, stream>>>(att, Wout_bf, out);
}